// Round 2
// baseline (1450.926 us; speedup 1.0000x reference)
//
#include <hip/hip_runtime.h>
#include <hip/hip_bf16.h>
#include <cstdint>

#define N_NODES 100000
#define N_EDGES 3200000
#define NFEAT   256
#define NCLASS  40

// bucket sort params: bucket = row >> 7 (128 rows/bucket)
#define BROWS_LOG 7
#define BROWS     128
#define NBUCK     782      // ceil(100000/128)
#define CHUNK     8192     // edges per block in phase 1
#define NBLK      391      // ceil(3200000/8192)
#define GHN       (NBUCK * NBLK)   // 305762

// persistent-GEMM weight-tile pitch (ushorts). 264*2=528 B/row: 16B-aligned,
// 528/4=132 dwords ≡ 4 (mod 32) -> ds_read_b128 across m=0..15 lands 2 lanes/bank
// (free per m136). Full WT tile: 256*264*2 = 135168 B (dynamic LDS, 1 block/CU).
#define GP 264
#define GEMM_TILES 782     // ceil(100000/128)

typedef __bf16 bf16;
typedef __attribute__((ext_vector_type(8))) __bf16 bf16x8;
typedef __attribute__((ext_vector_type(4))) float f32x4;
typedef __attribute__((ext_vector_type(2))) float f32x2;

__device__ inline float b2f(unsigned short u) {
    union { unsigned int i; float f; } x; x.i = ((unsigned int)u) << 16; return x.f;
}
__device__ inline unsigned short f2b(float f) {
    union { float f; unsigned int i; } x; x.f = f;
    unsigned int i = x.i;
    return (unsigned short)((i + 0x7fffu + ((i >> 16) & 1u)) >> 16);
}
__device__ inline f32x2 unpack2(unsigned int d) {
    union { unsigned int i; float f; } lo, hi;
    lo.i = d << 16;
    hi.i = d & 0xFFFF0000u;
    return (f32x2){lo.f, hi.f};
}
__device__ inline unsigned int pack2(f32x2 a) {
    return ((unsigned int)f2b(a[0])) | (((unsigned int)f2b(a[1])) << 16);
}

// ---------------- weight transposes (fp32 W[k][n] -> bf16 WT[n][k]) ----------------
__global__ void prep_w_kernel(const float* __restrict__ W1, const float* __restrict__ W2,
                              const float* __restrict__ W3, const float* __restrict__ W4,
                              unsigned short* __restrict__ WT1, unsigned short* __restrict__ WT2,
                              unsigned short* __restrict__ WT3, unsigned short* __restrict__ WT4) {
    int i = blockIdx.x * blockDim.x + threadIdx.x;
    if (i < 256 * 256) {
        int nIdx = i >> 8, k = i & 255;
        WT1[i] = f2b(W1[k * 256 + nIdx]);
        WT2[i] = f2b(W2[k * 256 + nIdx]);
        WT3[i] = f2b(W3[k * 256 + nIdx]);
    }
    if (i < 48 * 256) {
        int nIdx = i >> 8, k = i & 255;
        WT4[i] = (nIdx < NCLASS) ? f2b(W4[k * NCLASS + nIdx]) : (unsigned short)0;
    }
}

// ---------------- fp32 -> bf16 cast ----------------
__global__ void cast_kernel(const float* __restrict__ X, unsigned short* __restrict__ Y, int n4) {
    int i = blockIdx.x * blockDim.x + threadIdx.x;
    if (i >= n4) return;
    float4 v = *(const float4*)(X + (size_t)i * 4);
    ushort4 o;
    o.x = f2b(v.x); o.y = f2b(v.y); o.z = f2b(v.z); o.w = f2b(v.w);
    *(ushort4*)(Y + (size_t)i * 4) = o;
}

// ---------------- P1a: per-(block,bucket) histogram (LDS only) ----------------
__global__ __launch_bounds__(256) void p1a_kernel(const int* __restrict__ erow,
                                                  int* __restrict__ ghist) {
    __shared__ int h[NBUCK];
    for (int j = threadIdx.x; j < NBUCK; j += 256) h[j] = 0;
    __syncthreads();
    int base = blockIdx.x * CHUNK;
    for (int j = 0; j < CHUNK; j += 256) {
        int i = base + j + threadIdx.x;
        if (i < N_EDGES) atomicAdd(&h[erow[i] >> BROWS_LOG], 1);
    }
    __syncthreads();
    for (int j = threadIdx.x; j < NBUCK; j += 256)
        ghist[(size_t)j * NBLK + blockIdx.x] = h[j];
}

// ---------------- in-place exclusive scan over ghist (GHN ints) ----------------
__global__ void scanB_blocks_kernel(int* __restrict__ g, int* __restrict__ bsums, int n) {
    __shared__ int s[1024];
    int i = blockIdx.x * 1024 + threadIdx.x;
    int v = (i < n) ? g[i] : 0;
    s[threadIdx.x] = v;
    __syncthreads();
    for (int off = 1; off < 1024; off <<= 1) {
        int t = (threadIdx.x >= off) ? s[threadIdx.x - off] : 0;
        __syncthreads();
        s[threadIdx.x] += t;
        __syncthreads();
    }
    if (i < n) g[i] = s[threadIdx.x] - v;
    if (threadIdx.x == 1023) bsums[blockIdx.x] = s[1023];
}

__global__ void scanB_sums_kernel(int* __restrict__ bsums, int nb) {
    __shared__ int s[512];
    int v = (threadIdx.x < nb) ? bsums[threadIdx.x] : 0;
    s[threadIdx.x] = v;
    __syncthreads();
    for (int off = 1; off < 512; off <<= 1) {
        int t = (threadIdx.x >= off) ? s[threadIdx.x - off] : 0;
        __syncthreads();
        s[threadIdx.x] += t;
        __syncthreads();
    }
    if (threadIdx.x < nb) bsums[threadIdx.x] = s[threadIdx.x] - v;  // exclusive
}

__global__ void scanB_add_kernel(int* __restrict__ g, const int* __restrict__ bsums, int n) {
    int i = blockIdx.x * blockDim.x + threadIdx.x;
    if (i < n) g[i] += bsums[i >> 10];
}

// ---------------- P1c: bucket scatter via LDS cursors (no global atomics) ----------------
__global__ __launch_bounds__(256) void p1c_kernel(const int* __restrict__ erow,
                                                  const int* __restrict__ ecol,
                                                  const float* __restrict__ ew,
                                                  const int* __restrict__ ghist,
                                                  uint2* __restrict__ stage) {
    __shared__ int cur[NBUCK];
    for (int j = threadIdx.x; j < NBUCK; j += 256)
        cur[j] = ghist[(size_t)j * NBLK + blockIdx.x];
    __syncthreads();
    int base = blockIdx.x * CHUNK;
    for (int j = 0; j < CHUNK; j += 1024) {
        int r[4], c[4]; float w[4]; bool m[4];
#pragma unroll
        for (int q = 0; q < 4; q++) {
            int i = base + j + q * 256 + threadIdx.x;
            m[q] = (i < N_EDGES);
            if (m[q]) { r[q] = erow[i]; c[q] = ecol[i]; w[q] = ew[i]; }
        }
#pragma unroll
        for (int q = 0; q < 4; q++) {
            if (m[q]) {
                unsigned int qq = (unsigned int)(w[q] * 32768.f + 0.5f);
                if (qq > 32767u) qq = 32767u;
                int p = atomicAdd(&cur[r[q] >> BROWS_LOG], 1);
                stage[p] = make_uint2((unsigned int)r[q], (((unsigned int)c[q]) << 15) | qq);
            }
        }
    }
}

// ---------------- P2: per-bucket local sort -> final edges + rowptr ----------------
__global__ __launch_bounds__(256) void p2_kernel(const int* __restrict__ ghist,
                                                 const uint2* __restrict__ stage,
                                                 unsigned int* __restrict__ edges,
                                                 int* __restrict__ rowptr) {
    __shared__ int h[BROWS], sc[BROWS], lcur[BROWS];
    int b = blockIdx.x;
    int lo = ghist[(size_t)b * NBLK];
    int hi = (b + 1 < NBUCK) ? ghist[(size_t)(b + 1) * NBLK] : N_EDGES;
    if (threadIdx.x < BROWS) h[threadIdx.x] = 0;
    __syncthreads();
    for (int i = lo + threadIdx.x; i < hi; i += 256)
        atomicAdd(&h[stage[i].x & (BROWS - 1)], 1);
    __syncthreads();
    if (threadIdx.x < BROWS) sc[threadIdx.x] = h[threadIdx.x];
    __syncthreads();
    for (int off = 1; off < BROWS; off <<= 1) {
        int t = 0;
        if (threadIdx.x < BROWS && threadIdx.x >= off) t = sc[threadIdx.x - off];
        __syncthreads();
        if (threadIdx.x < BROWS) sc[threadIdx.x] += t;
        __syncthreads();
    }
    if (threadIdx.x < BROWS) {
        int ex = sc[threadIdx.x] - h[threadIdx.x];   // exclusive
        int row = b * BROWS + threadIdx.x;
        if (row <= N_NODES) rowptr[row] = lo + ex;   // covers rowptr[N] exactly once
        lcur[threadIdx.x] = lo + ex;
    }
    __syncthreads();
    for (int i = lo + threadIdx.x; i < hi; i += 256) {
        uint2 sd = stage[i];
        int p = atomicAdd(&lcur[sd.x & (BROWS - 1)], 1);
        edges[p] = sd.y;
    }
}

// ---------------- SpMM + residual: Y = X + A*X (bf16 X/Y) ----------------
// (proven round-0 kernel, unchanged: 73% occupancy, ~3.7 TB/s)
__global__ void spmm_res_kernel(const unsigned short* __restrict__ X, unsigned short* __restrict__ Y,
                                const int* __restrict__ rowptr, const unsigned int* __restrict__ edges,
                                int n) {
    int gtid = blockIdx.x * blockDim.x + threadIdx.x;
    int row = gtid >> 6;
    int lane = gtid & 63;
    if (row >= n) return;
    const int half = lane >> 5;
    const int fb = (lane & 31) * 8;

    f32x2 acc[4];
    {
        uint4 xb = *(const uint4*)(X + (size_t)row * NFEAT + fb);
        if (half == 0) {
            acc[0] = unpack2(xb.x); acc[1] = unpack2(xb.y);
            acc[2] = unpack2(xb.z); acc[3] = unpack2(xb.w);
        } else {
            acc[0] = (f32x2){0.f, 0.f}; acc[1] = (f32x2){0.f, 0.f};
            acc[2] = (f32x2){0.f, 0.f}; acc[3] = (f32x2){0.f, 0.f};
        }
    }

    int s = rowptr[row], e = rowptr[row + 1];
    for (int k = s; k < e; k += 12) {
        int   c[6];
        f32x2 w2[6];
#pragma unroll
        for (int j = 0; j < 6; j++) {
            int kj = k + j * 2 + half;
            int kc = (kj < e) ? kj : (e - 1);
            unsigned int d = edges[kc];
            c[j] = (int)(d >> 15);
            float w = (kj < e) ? (float)(d & 32767u) * (1.f / 32768.f) : 0.f;
            w2[j] = (f32x2){w, w};
        }
        uint4 v[6];
#pragma unroll
        for (int j = 0; j < 6; j++) v[j] = *(const uint4*)(X + (size_t)c[j] * NFEAT + fb);
#pragma unroll
        for (int j = 0; j < 6; j++) {
            acc[0] += w2[j] * unpack2(v[j].x);
            acc[1] += w2[j] * unpack2(v[j].y);
            acc[2] += w2[j] * unpack2(v[j].z);
            acc[3] += w2[j] * unpack2(v[j].w);
        }
    }

#pragma unroll
    for (int i = 0; i < 4; i++) {
        acc[i][0] += __shfl_xor(acc[i][0], 32, 64);
        acc[i][1] += __shfl_xor(acc[i][1], 32, 64);
    }
    if (half == 0) {
        uint4 o;
        o.x = pack2(acc[0]); o.y = pack2(acc[1]);
        o.z = pack2(acc[2]); o.w = pack2(acc[3]);
        *(uint4*)(Y + (size_t)row * NFEAT + fb) = o;
    }
}

// ---------------- persistent MFMA GEMM: full WT resident in LDS ----------------
// 512 threads (8 waves), grid 256 (1 block/CU; 132 KB dynamic LDS).
// Stage WT once, ONE barrier, then barrier-free grid-stride loop over 128-row
// tiles: each wave owns 16 rows x 256 cols (16 MFMA x 8 k-chunks from LDS).
__global__ __launch_bounds__(512) void gemm_relu_persist_kernel(
    const bf16* __restrict__ X, const unsigned short* __restrict__ WT,
    const float* __restrict__ bias, unsigned short* __restrict__ Y, int M) {
    extern __shared__ unsigned short sW[];        // [256][GP]
    const int tid = threadIdx.x;
    const int wave = tid >> 6;
    const int lane = tid & 63;
    const int m = lane & 15;
    const int quad = lane >> 4;

    // stage all of WT (256 cols x 256 k): 8192 uint4, 16 per thread
    for (int f = tid; f < 8192; f += 512) {
        int n = f >> 5, j = f & 31;
        uint4 v = *(const uint4*)(WT + (size_t)n * NFEAT + j * 8);
        *(uint4*)&sW[n * GP + j * 8] = v;
    }
    // hoist bias (col = t*16+m is loop-invariant)
    float bv[16];
#pragma unroll
    for (int t = 0; t < 16; t++) bv[t] = bias[t * 16 + m];
    __syncthreads();

    for (int tile = blockIdx.x; tile < GEMM_TILES; tile += gridDim.x) {
        const int rowBase = tile * 128 + wave * 16;
        int arow = rowBase + m;
        if (arow >= M) arow = M - 1;
        const bf16* xp = X + (size_t)arow * NFEAT + quad * 8;
        bf16x8 a[8];
#pragma unroll
        for (int k = 0; k < 8; k++) a[k] = *(const bf16x8*)(xp + k * 32);
        f32x4 acc[16];
#pragma unroll
        for (int t = 0; t < 16; t++) acc[t] = (f32x4){0.f, 0.f, 0.f, 0.f};
#pragma unroll
        for (int k = 0; k < 8; k++) {
#pragma unroll
            for (int t = 0; t < 16; t++) {
                bf16x8 b = *(const bf16x8*)&sW[(t * 16 + m) * GP + k * 32 + quad * 8];
                acc[t] = __builtin_amdgcn_mfma_f32_16x16x32_bf16(a[k], b, acc[t], 0, 0, 0);
            }
        }
#pragma unroll
        for (int t = 0; t < 16; t++) {
            int col = t * 16 + m;
#pragma unroll
            for (int r = 0; r < 4; r++) {
                int row = rowBase + quad * 4 + r;
                if (row < M) {
                    float v = fmaxf(acc[t][r] + bv[t], 0.f);
                    Y[(size_t)row * NFEAT + col] = f2b(v);
                }
            }
        }
    }
}

// ---------------- final GEMM (48 cols) + fused log_softmax, weight-resident ----------------
// 512 threads (8 waves) x 128 rows per block, grid 782. 25 KB static LDS.
__global__ __launch_bounds__(512) void gemm_ls_persist_kernel(
    const bf16* __restrict__ X, const unsigned short* __restrict__ WT,
    const float* __restrict__ bias, float* __restrict__ out, int M) {
    __shared__ unsigned short sW[48 * GP];
    const int tid = threadIdx.x;
    const int wave = tid >> 6;
    const int lane = tid & 63;
    const int m = lane & 15;
    const int quad = lane >> 4;

    for (int f = tid; f < 1536; f += 512) {
        int n = f >> 5, j = f & 31;
        uint4 v = *(const uint4*)(WT + (size_t)n * NFEAT + j * 8);
        *(uint4*)&sW[n * GP + j * 8] = v;
    }
    __syncthreads();

    const int rowBase = blockIdx.x * 128 + wave * 16;
    int arow = rowBase + m;
    if (arow >= M) arow = M - 1;
    const bf16* xp = X + (size_t)arow * NFEAT + quad * 8;
    bf16x8 a[8];
#pragma unroll
    for (int k = 0; k < 8; k++) a[k] = *(const bf16x8*)(xp + k * 32);
    f32x4 acc[3];
#pragma unroll
    for (int t = 0; t < 3; t++) acc[t] = (f32x4){0.f, 0.f, 0.f, 0.f};
#pragma unroll
    for (int k = 0; k < 8; k++) {
#pragma unroll
        for (int t = 0; t < 3; t++) {
            bf16x8 b = *(const bf16x8*)&sW[(t * 16 + m) * GP + k * 32 + quad * 8];
            acc[t] = __builtin_amdgcn_mfma_f32_16x16x32_bf16(a[k], b, acc[t], 0, 0, 0);
        }
    }

    float v[3][4];
    bool valid[3];
#pragma unroll
    for (int t = 0; t < 3; t++) {
        int col = t * 16 + m;
        valid[t] = (col < NCLASS);
        float bvv = valid[t] ? bias[col] : 0.f;
#pragma unroll
        for (int r = 0; r < 4; r++) v[t][r] = acc[t][r] + bvv;
    }

#pragma unroll
    for (int r = 0; r < 4; r++) {
        int row = rowBase + quad * 4 + r;
        float mx = -1e30f;
#pragma unroll
        for (int t = 0; t < 3; t++) if (valid[t]) mx = fmaxf(mx, v[t][r]);
#pragma unroll
        for (int off = 1; off < 16; off <<= 1) mx = fmaxf(mx, __shfl_xor(mx, off, 64));
        float sm = 0.f;
#pragma unroll
        for (int t = 0; t < 3; t++) if (valid[t]) sm += __expf(v[t][r] - mx);
#pragma unroll
        for (int off = 1; off < 16; off <<= 1) sm += __shfl_xor(sm, off, 64);
        float ls = __logf(sm);
        if (row < M) {
#pragma unroll
            for (int t = 0; t < 3; t++) {
                int col = t * 16 + m;
                if (col < NCLASS)
                    out[(size_t)row * NCLASS + col] = v[t][r] - mx - ls;
            }
        }
    }
}

extern "C" void kernel_launch(void* const* d_in, const int* in_sizes, int n_in,
                              void* d_out, int out_size, void* d_ws, size_t ws_size,
                              hipStream_t stream) {
    const float* x   = (const float*)d_in[0];
    const int* erow  = (const int*)d_in[1];
    const int* ecol  = (const int*)d_in[2];
    const float* ew  = (const float*)d_in[3];
    const float* W1  = (const float*)d_in[4];
    const float* W2  = (const float*)d_in[6];
    const float* W3  = (const float*)d_in[8];
    const float* W4  = (const float*)d_in[10];
    const float* b1  = (const float*)d_in[5];
    const float* b2  = (const float*)d_in[7];
    const float* b3  = (const float*)d_in[9];
    const float* b4  = (const float*)d_in[11];

    char* ws = (char*)d_ws;
    size_t off = 0;
    auto alloc = [&](size_t bytes) -> char* {
        char* p = ws + off;
        off = (off + bytes + 255) & ~(size_t)255;
        return p;
    };
    // stage (25.6 MB) aliases the front of hA: stage's lifetime is [p1c, p2];
    // hA is written by cast_kernel AFTER p2. hB reuses the x input buffer
    // (fp32 x dead after cast; harness restores d_in before every launch).
    int* rowptr  = (int*)alloc((size_t)(N_NODES + 1) * 4);
    int* bsumsB  = (int*)alloc(512 * 4);
    unsigned int* edges = (unsigned int*)alloc((size_t)N_EDGES * 4);  // packed col|w
    int* ghist   = (int*)alloc((size_t)GHN * 4);
    unsigned short* WT1 = (unsigned short*)alloc(256 * 256 * 2);
    unsigned short* WT2 = (unsigned short*)alloc(256 * 256 * 2);
    unsigned short* WT3 = (unsigned short*)alloc(256 * 256 * 2);
    unsigned short* WT4 = (unsigned short*)alloc(48 * 256 * 2);
    unsigned short* hA  = (unsigned short*)alloc((size_t)N_NODES * NFEAT * 2);
    uint2* stage        = (uint2*)hA;                      // aliased (see above)
    unsigned short* hB  = (unsigned short*)d_in[0];
    (void)ws_size; (void)n_in; (void)in_sizes; (void)out_size;

    // ---- atomic-free CSR build ----
    prep_w_kernel<<<(256 * 256 + 255) / 256, 256, 0, stream>>>(
        W1, W2, W3, W4, WT1, WT2, WT3, WT4);
    p1a_kernel<<<NBLK, 256, 0, stream>>>(erow, ghist);
    int nsb = (GHN + 1023) / 1024;   // 299
    scanB_blocks_kernel<<<nsb, 1024, 0, stream>>>(ghist, bsumsB, GHN);
    scanB_sums_kernel<<<1, 512, 0, stream>>>(bsumsB, nsb);
    scanB_add_kernel<<<(GHN + 255) / 256, 256, 0, stream>>>(ghist, bsumsB, GHN);
    p1c_kernel<<<NBLK, 256, 0, stream>>>(erow, ecol, ew, ghist, stage);
    p2_kernel<<<NBUCK, 256, 0, stream>>>(ghist, stage, edges, rowptr);

    // ---- forward pass ----
    const int n4 = N_NODES * NFEAT / 4;
    const int spmm_grid = (N_NODES * 64 + 255) / 256;
    const size_t gemm_lds = (size_t)256 * GP * 2;   // 135168 B dynamic LDS

    // xb16 = bf16(x)  (after p2: stage region is dead, hA is safe to write)
    cast_kernel<<<(n4 + 255) / 256, 256, 0, stream>>>(x, hA, n4);
    // h0 = x + A x           (gather bf16 hA -> hB)
    spmm_res_kernel<<<spmm_grid, 256, 0, stream>>>(hA, hB, rowptr, edges, N_NODES);
    // h1 = relu(h0 W1 + b1)  (in-place hB)
    gemm_relu_persist_kernel<<<256, 512, gemm_lds, stream>>>(
        (const bf16*)hB, WT1, b1, hB, N_NODES);
    // h2 = relu(h1 W2 + b2)  (in-place hB)
    gemm_relu_persist_kernel<<<256, 512, gemm_lds, stream>>>(
        (const bf16*)hB, WT2, b2, hB, N_NODES);
    // h3 = h2 + A h2         (gather bf16 hB -> hA)
    spmm_res_kernel<<<spmm_grid, 256, 0, stream>>>(hB, hA, rowptr, edges, N_NODES);
    // h4 = relu(h3 W3 + b3)  (in-place hA)
    gemm_relu_persist_kernel<<<256, 512, gemm_lds, stream>>>(
        (const bf16*)hA, WT3, b3, hA, N_NODES);
    // out = log_softmax(h4 W4 + b4)
    gemm_ls_persist_kernel<<<GEMM_TILES, 512, 0, stream>>>(
        (const bf16*)hA, WT4, b4, (float*)d_out, N_NODES);
}

// Round 3
// 926.813 us; speedup vs baseline: 1.5655x; 1.5655x over previous
//
#include <hip/hip_runtime.h>
#include <hip/hip_bf16.h>
#include <cstdint>

#define N_NODES 100000
#define N_EDGES 3200000
#define NFEAT   256
#define NCLASS  40

// bucket sort params: bucket = row >> 7 (128 rows/bucket)
#define BROWS_LOG 7
#define BROWS     128
#define NBUCK     782      // ceil(100000/128)
#define CHUNK     8192     // edges per block in phase 1
#define NBLK      391      // ceil(3200000/8192)
#define GHN       (NBUCK * NBLK)   // 305762

typedef __bf16 bf16;
typedef __attribute__((ext_vector_type(8))) __bf16 bf16x8;
typedef __attribute__((ext_vector_type(4))) float f32x4;
typedef __attribute__((ext_vector_type(2))) float f32x2;

__device__ inline float b2f(unsigned short u) {
    union { unsigned int i; float f; } x; x.i = ((unsigned int)u) << 16; return x.f;
}
__device__ inline unsigned short f2b(float f) {
    union { float f; unsigned int i; } x; x.f = f;
    unsigned int i = x.i;
    return (unsigned short)((i + 0x7fffu + ((i >> 16) & 1u)) >> 16);
}
__device__ inline f32x2 unpack2(unsigned int d) {
    union { unsigned int i; float f; } lo, hi;
    lo.i = d << 16;
    hi.i = d & 0xFFFF0000u;
    return (f32x2){lo.f, hi.f};
}
__device__ inline unsigned int pack2(f32x2 a) {
    return ((unsigned int)f2b(a[0])) | (((unsigned int)f2b(a[1])) << 16);
}

// ---------------- weight transposes (fp32 W[k][n] -> bf16 WT[n][k]) ----------------
__global__ void prep_w_kernel(const float* __restrict__ W1, const float* __restrict__ W2,
                              const float* __restrict__ W3, const float* __restrict__ W4,
                              unsigned short* __restrict__ WT1, unsigned short* __restrict__ WT2,
                              unsigned short* __restrict__ WT3, unsigned short* __restrict__ WT4) {
    int i = blockIdx.x * blockDim.x + threadIdx.x;
    if (i < 256 * 256) {
        int nIdx = i >> 8, k = i & 255;
        WT1[i] = f2b(W1[k * 256 + nIdx]);
        WT2[i] = f2b(W2[k * 256 + nIdx]);
        WT3[i] = f2b(W3[k * 256 + nIdx]);
    }
    if (i < 48 * 256) {
        int nIdx = i >> 8, k = i & 255;
        WT4[i] = (nIdx < NCLASS) ? f2b(W4[k * NCLASS + nIdx]) : (unsigned short)0;
    }
}

// ---------------- fp32 -> bf16 cast ----------------
__global__ void cast_kernel(const float* __restrict__ X, unsigned short* __restrict__ Y, int n4) {
    int i = blockIdx.x * blockDim.x + threadIdx.x;
    if (i >= n4) return;
    float4 v = *(const float4*)(X + (size_t)i * 4);
    ushort4 o;
    o.x = f2b(v.x); o.y = f2b(v.y); o.z = f2b(v.z); o.w = f2b(v.w);
    *(ushort4*)(Y + (size_t)i * 4) = o;
}

// ---------------- P1a: per-(block,bucket) histogram (LDS only) ----------------
__global__ __launch_bounds__(256) void p1a_kernel(const int* __restrict__ erow,
                                                  int* __restrict__ ghist) {
    __shared__ int h[NBUCK];
    for (int j = threadIdx.x; j < NBUCK; j += 256) h[j] = 0;
    __syncthreads();
    int base = blockIdx.x * CHUNK;
    for (int j = 0; j < CHUNK; j += 256) {
        int i = base + j + threadIdx.x;
        if (i < N_EDGES) atomicAdd(&h[erow[i] >> BROWS_LOG], 1);
    }
    __syncthreads();
    for (int j = threadIdx.x; j < NBUCK; j += 256)
        ghist[(size_t)j * NBLK + blockIdx.x] = h[j];
}

// ---------------- in-place exclusive scan over ghist (GHN ints) ----------------
__global__ void scanB_blocks_kernel(int* __restrict__ g, int* __restrict__ bsums, int n) {
    __shared__ int s[1024];
    int i = blockIdx.x * 1024 + threadIdx.x;
    int v = (i < n) ? g[i] : 0;
    s[threadIdx.x] = v;
    __syncthreads();
    for (int off = 1; off < 1024; off <<= 1) {
        int t = (threadIdx.x >= off) ? s[threadIdx.x - off] : 0;
        __syncthreads();
        s[threadIdx.x] += t;
        __syncthreads();
    }
    if (i < n) g[i] = s[threadIdx.x] - v;
    if (threadIdx.x == 1023) bsums[blockIdx.x] = s[1023];
}

__global__ void scanB_sums_kernel(int* __restrict__ bsums, int nb) {
    __shared__ int s[512];
    int v = (threadIdx.x < nb) ? bsums[threadIdx.x] : 0;
    s[threadIdx.x] = v;
    __syncthreads();
    for (int off = 1; off < 512; off <<= 1) {
        int t = (threadIdx.x >= off) ? s[threadIdx.x - off] : 0;
        __syncthreads();
        s[threadIdx.x] += t;
        __syncthreads();
    }
    if (threadIdx.x < nb) bsums[threadIdx.x] = s[threadIdx.x] - v;  // exclusive
}

__global__ void scanB_add_kernel(int* __restrict__ g, const int* __restrict__ bsums, int n) {
    int i = blockIdx.x * blockDim.x + threadIdx.x;
    if (i < n) g[i] += bsums[i >> 10];
}

// ---------------- P1c: bucket scatter via LDS cursors (no global atomics) ----------------
__global__ __launch_bounds__(256) void p1c_kernel(const int* __restrict__ erow,
                                                  const int* __restrict__ ecol,
                                                  const float* __restrict__ ew,
                                                  const int* __restrict__ ghist,
                                                  uint2* __restrict__ stage) {
    __shared__ int cur[NBUCK];
    for (int j = threadIdx.x; j < NBUCK; j += 256)
        cur[j] = ghist[(size_t)j * NBLK + blockIdx.x];
    __syncthreads();
    int base = blockIdx.x * CHUNK;
    for (int j = 0; j < CHUNK; j += 1024) {
        int r[4], c[4]; float w[4]; bool m[4];
#pragma unroll
        for (int q = 0; q < 4; q++) {
            int i = base + j + q * 256 + threadIdx.x;
            m[q] = (i < N_EDGES);
            if (m[q]) { r[q] = erow[i]; c[q] = ecol[i]; w[q] = ew[i]; }
        }
#pragma unroll
        for (int q = 0; q < 4; q++) {
            if (m[q]) {
                unsigned int qq = (unsigned int)(w[q] * 32768.f + 0.5f);
                if (qq > 32767u) qq = 32767u;
                int p = atomicAdd(&cur[r[q] >> BROWS_LOG], 1);
                stage[p] = make_uint2((unsigned int)r[q], (((unsigned int)c[q]) << 15) | qq);
            }
        }
    }
}

// ---------------- P2: per-bucket local sort -> final edges + rowptr ----------------
__global__ __launch_bounds__(256) void p2_kernel(const int* __restrict__ ghist,
                                                 const uint2* __restrict__ stage,
                                                 unsigned int* __restrict__ edges,
                                                 int* __restrict__ rowptr) {
    __shared__ int h[BROWS], sc[BROWS], lcur[BROWS];
    int b = blockIdx.x;
    int lo = ghist[(size_t)b * NBLK];
    int hi = (b + 1 < NBUCK) ? ghist[(size_t)(b + 1) * NBLK] : N_EDGES;
    if (threadIdx.x < BROWS) h[threadIdx.x] = 0;
    __syncthreads();
    for (int i = lo + threadIdx.x; i < hi; i += 256)
        atomicAdd(&h[stage[i].x & (BROWS - 1)], 1);
    __syncthreads();
    if (threadIdx.x < BROWS) sc[threadIdx.x] = h[threadIdx.x];
    __syncthreads();
    for (int off = 1; off < BROWS; off <<= 1) {
        int t = 0;
        if (threadIdx.x < BROWS && threadIdx.x >= off) t = sc[threadIdx.x - off];
        __syncthreads();
        if (threadIdx.x < BROWS) sc[threadIdx.x] += t;
        __syncthreads();
    }
    if (threadIdx.x < BROWS) {
        int ex = sc[threadIdx.x] - h[threadIdx.x];   // exclusive
        int row = b * BROWS + threadIdx.x;
        if (row <= N_NODES) rowptr[row] = lo + ex;   // covers rowptr[N] exactly once
        lcur[threadIdx.x] = lo + ex;
    }
    __syncthreads();
    for (int i = lo + threadIdx.x; i < hi; i += 256) {
        uint2 sd = stage[i];
        int p = atomicAdd(&lcur[sd.x & (BROWS - 1)], 1);
        edges[p] = sd.y;
    }
}

// ---------------- SpMM + residual: Y = X + A*X (bf16 X/Y) ----------------
// (proven kernel, unchanged: 73% occupancy, ~3.7 TB/s)
__global__ void spmm_res_kernel(const unsigned short* __restrict__ X, unsigned short* __restrict__ Y,
                                const int* __restrict__ rowptr, const unsigned int* __restrict__ edges,
                                int n) {
    int gtid = blockIdx.x * blockDim.x + threadIdx.x;
    int row = gtid >> 6;
    int lane = gtid & 63;
    if (row >= n) return;
    const int half = lane >> 5;
    const int fb = (lane & 31) * 8;

    f32x2 acc[4];
    {
        uint4 xb = *(const uint4*)(X + (size_t)row * NFEAT + fb);
        if (half == 0) {
            acc[0] = unpack2(xb.x); acc[1] = unpack2(xb.y);
            acc[2] = unpack2(xb.z); acc[3] = unpack2(xb.w);
        } else {
            acc[0] = (f32x2){0.f, 0.f}; acc[1] = (f32x2){0.f, 0.f};
            acc[2] = (f32x2){0.f, 0.f}; acc[3] = (f32x2){0.f, 0.f};
        }
    }

    int s = rowptr[row], e = rowptr[row + 1];
    for (int k = s; k < e; k += 12) {
        int   c[6];
        f32x2 w2[6];
#pragma unroll
        for (int j = 0; j < 6; j++) {
            int kj = k + j * 2 + half;
            int kc = (kj < e) ? kj : (e - 1);
            unsigned int d = edges[kc];
            c[j] = (int)(d >> 15);
            float w = (kj < e) ? (float)(d & 32767u) * (1.f / 32768.f) : 0.f;
            w2[j] = (f32x2){w, w};
        }
        uint4 v[6];
#pragma unroll
        for (int j = 0; j < 6; j++) v[j] = *(const uint4*)(X + (size_t)c[j] * NFEAT + fb);
#pragma unroll
        for (int j = 0; j < 6; j++) {
            acc[0] += w2[j] * unpack2(v[j].x);
            acc[1] += w2[j] * unpack2(v[j].y);
            acc[2] += w2[j] * unpack2(v[j].z);
            acc[3] += w2[j] * unpack2(v[j].w);
        }
    }

#pragma unroll
    for (int i = 0; i < 4; i++) {
        acc[i][0] += __shfl_xor(acc[i][0], 32, 64);
        acc[i][1] += __shfl_xor(acc[i][1], 32, 64);
    }
    if (half == 0) {
        uint4 o;
        o.x = pack2(acc[0]); o.y = pack2(acc[1]);
        o.z = pack2(acc[2]); o.w = pack2(acc[3]);
        *(uint4*)(Y + (size_t)row * NFEAT + fb) = o;
    }
}

// ---------------- MFMA GEMM with LDS-staged WT (SWAPPED operands) ----------------
// mfma(WT_frag, X_frag): D = C^T per tile -> lane (m,quad) owns node row
// rowBase+m with cols t*16+quad*4+{0..3}. Epilogue: 8-B contiguous uint2
// stores (4x fewer, 4x wider than the old 2-B scatter); one uniform row<M
// predicate. Numerically identical to the unswapped version.
template <int NT>
__global__ __launch_bounds__(256) void gemm_relu_kernel(
    const bf16* __restrict__ X, const bf16* __restrict__ WT,
    const float* __restrict__ bias,
    unsigned short* __restrict__ Y, int M) {
    constexpr int NROWS = NT * 16;
    __shared__ unsigned int sB[NROWS * 20];
    const int tid = threadIdx.x;
    const int wave = tid >> 6;
    const int lane = tid & 63;
    const int m = lane & 15;
    const int quad = lane >> 4;
    const int rowBase = blockIdx.x * 64 + wave * 16;
    int arow = rowBase + m;
    if (arow >= M) arow = M - 1;

    f32x4 acc[NT];
#pragma unroll
    for (int t = 0; t < NT; t++) acc[t] = (f32x4){0.f, 0.f, 0.f, 0.f};

    const bf16* xp = X + (size_t)arow * NFEAT + quad * 8;
#pragma unroll
    for (int k0 = 0; k0 < NFEAT; k0 += 32) {
#pragma unroll
        for (int f = tid; f < NROWS * 4; f += 256) {
            int n = f >> 2, j = f & 3;
            uint4 v = *(const uint4*)(WT + (size_t)n * NFEAT + k0 + j * 8);
            *(uint4*)&sB[n * 20 + j * 4] = v;
        }
        __syncthreads();
        bf16x8 a = *(const bf16x8*)(xp + k0);
#pragma unroll
        for (int t = 0; t < NT; t++) {
            bf16x8 b = *(const bf16x8*)&sB[(t * 16 + m) * 20 + quad * 4];
            acc[t] = __builtin_amdgcn_mfma_f32_16x16x32_bf16(b, a, acc[t], 0, 0, 0);
        }
        __syncthreads();
    }

    const int row = rowBase + m;
    if (row < M) {
#pragma unroll
        for (int t = 0; t < NT; t++) {
            const float* bp = bias + t * 16 + quad * 4;
            f32x2 lo = (f32x2){fmaxf(acc[t][0] + bp[0], 0.f), fmaxf(acc[t][1] + bp[1], 0.f)};
            f32x2 hi = (f32x2){fmaxf(acc[t][2] + bp[2], 0.f), fmaxf(acc[t][3] + bp[3], 0.f)};
            uint2 o = make_uint2(pack2(lo), pack2(hi));
            *(uint2*)(Y + (size_t)row * NFEAT + t * 16 + quad * 4) = o;
        }
    }
}

// ---------------- final GEMM (40 cols padded to 48) + fused log_softmax (SWAPPED) ----------------
__global__ __launch_bounds__(256) void gemm_ls_kernel(
    const bf16* __restrict__ X, const bf16* __restrict__ WT,
    const float* __restrict__ bias,
    float* __restrict__ out, int M) {
    constexpr int NT = 3;
    constexpr int NROWS = NT * 16;
    __shared__ unsigned int sB[NROWS * 20];
    const int tid = threadIdx.x;
    const int wave = tid >> 6;
    const int lane = tid & 63;
    const int m = lane & 15;
    const int quad = lane >> 4;
    const int rowBase = blockIdx.x * 64 + wave * 16;
    int arow = rowBase + m;
    if (arow >= M) arow = M - 1;

    f32x4 acc[NT];
#pragma unroll
    for (int t = 0; t < NT; t++) acc[t] = (f32x4){0.f, 0.f, 0.f, 0.f};

    const bf16* xp = X + (size_t)arow * NFEAT + quad * 8;
#pragma unroll
    for (int k0 = 0; k0 < NFEAT; k0 += 32) {
        if (tid < NROWS * 4) {
            int n = tid >> 2, j = tid & 3;
            uint4 v = *(const uint4*)(WT + (size_t)n * NFEAT + k0 + j * 8);
            *(uint4*)&sB[n * 20 + j * 4] = v;
        }
        __syncthreads();
        bf16x8 a = *(const bf16x8*)(xp + k0);
#pragma unroll
        for (int t = 0; t < NT; t++) {
            bf16x8 b = *(const bf16x8*)&sB[(t * 16 + m) * 20 + quad * 4];
            acc[t] = __builtin_amdgcn_mfma_f32_16x16x32_bf16(b, a, acc[t], 0, 0, 0);
        }
        __syncthreads();
    }

    // lane (m,quad) owns row rowBase+m, cols t*16+quad*4+{0..3}
    // valid cols < 40: t=0,1 all; t=2 only quad<2.
    float v[3][4];
#pragma unroll
    for (int t = 0; t < 3; t++) {
        bool tv = (t < 2) || (quad < 2);
#pragma unroll
        for (int r = 0; r < 4; r++) {
            float bv = tv ? bias[t * 16 + quad * 4 + r] : 0.f;
            v[t][r] = tv ? (acc[t][r] + bv) : -1e30f;
        }
    }

    float mx = -1e30f;
#pragma unroll
    for (int t = 0; t < 3; t++)
#pragma unroll
        for (int r = 0; r < 4; r++) mx = fmaxf(mx, v[t][r]);
    mx = fmaxf(mx, __shfl_xor(mx, 16, 64));
    mx = fmaxf(mx, __shfl_xor(mx, 32, 64));

    float sm = 0.f;
#pragma unroll
    for (int t = 0; t < 3; t++) {
        bool tv = (t < 2) || (quad < 2);
        if (tv) {
#pragma unroll
            for (int r = 0; r < 4; r++) sm += __expf(v[t][r] - mx);
        }
    }
    sm += __shfl_xor(sm, 16, 64);
    sm += __shfl_xor(sm, 32, 64);
    float ls = __logf(sm);

    const int row = rowBase + m;
    if (row < M) {
#pragma unroll
        for (int t = 0; t < 3; t++) {
            if ((t < 2) || (quad < 2)) {
                f32x4 o = (f32x4){v[t][0] - mx - ls, v[t][1] - mx - ls,
                                  v[t][2] - mx - ls, v[t][3] - mx - ls};
                *(f32x4*)(out + (size_t)row * NCLASS + t * 16 + quad * 4) = o;
            }
        }
    }
}

extern "C" void kernel_launch(void* const* d_in, const int* in_sizes, int n_in,
                              void* d_out, int out_size, void* d_ws, size_t ws_size,
                              hipStream_t stream) {
    const float* x   = (const float*)d_in[0];
    const int* erow  = (const int*)d_in[1];
    const int* ecol  = (const int*)d_in[2];
    const float* ew  = (const float*)d_in[3];
    const float* W1  = (const float*)d_in[4];
    const float* W2  = (const float*)d_in[6];
    const float* W3  = (const float*)d_in[8];
    const float* W4  = (const float*)d_in[10];
    const float* b1  = (const float*)d_in[5];
    const float* b2  = (const float*)d_in[7];
    const float* b3  = (const float*)d_in[9];
    const float* b4  = (const float*)d_in[11];

    char* ws = (char*)d_ws;
    size_t off = 0;
    auto alloc = [&](size_t bytes) -> char* {
        char* p = ws + off;
        off = (off + bytes + 255) & ~(size_t)255;
        return p;
    };
    // stage (25.6 MB) aliases the front of hA: stage's lifetime is [p1c, p2];
    // hA is written by cast_kernel AFTER p2. hB reuses the x input buffer
    // (fp32 x dead after cast; harness restores d_in before every launch).
    int* rowptr  = (int*)alloc((size_t)(N_NODES + 1) * 4);
    int* bsumsB  = (int*)alloc(512 * 4);
    unsigned int* edges = (unsigned int*)alloc((size_t)N_EDGES * 4);  // packed col|w
    int* ghist   = (int*)alloc((size_t)GHN * 4);
    unsigned short* WT1 = (unsigned short*)alloc(256 * 256 * 2);
    unsigned short* WT2 = (unsigned short*)alloc(256 * 256 * 2);
    unsigned short* WT3 = (unsigned short*)alloc(256 * 256 * 2);
    unsigned short* WT4 = (unsigned short*)alloc(48 * 256 * 2);
    unsigned short* hA  = (unsigned short*)alloc((size_t)N_NODES * NFEAT * 2);
    uint2* stage        = (uint2*)hA;                      // aliased (see above)
    unsigned short* hB  = (unsigned short*)d_in[0];
    (void)ws_size; (void)n_in; (void)in_sizes; (void)out_size;

    // ---- atomic-free CSR build ----
    prep_w_kernel<<<(256 * 256 + 255) / 256, 256, 0, stream>>>(
        W1, W2, W3, W4, WT1, WT2, WT3, WT4);
    p1a_kernel<<<NBLK, 256, 0, stream>>>(erow, ghist);
    int nsb = (GHN + 1023) / 1024;   // 299
    scanB_blocks_kernel<<<nsb, 1024, 0, stream>>>(ghist, bsumsB, GHN);
    scanB_sums_kernel<<<1, 512, 0, stream>>>(bsumsB, nsb);
    scanB_add_kernel<<<(GHN + 255) / 256, 256, 0, stream>>>(ghist, bsumsB, GHN);
    p1c_kernel<<<NBLK, 256, 0, stream>>>(erow, ecol, ew, ghist, stage);
    p2_kernel<<<NBUCK, 256, 0, stream>>>(ghist, stage, edges, rowptr);

    // ---- forward pass ----
    const int n4 = N_NODES * NFEAT / 4;
    const int spmm_grid = (N_NODES * 64 + 255) / 256;
    const int gemm_grid = (N_NODES + 63) / 64;

    // xb16 = bf16(x)  (after p2: stage region is dead, hA is safe to write)
    cast_kernel<<<(n4 + 255) / 256, 256, 0, stream>>>(x, hA, n4);
    // h0 = x + A x           (gather bf16 hA -> hB)
    spmm_res_kernel<<<spmm_grid, 256, 0, stream>>>(hA, hB, rowptr, edges, N_NODES);
    // h1 = relu(h0 W1 + b1)  (in-place hB)
    gemm_relu_kernel<16><<<gemm_grid, 256, 0, stream>>>(
        (const bf16*)hB, (const bf16*)WT1, b1, hB, N_NODES);
    // h2 = relu(h1 W2 + b2)  (in-place hB)
    gemm_relu_kernel<16><<<gemm_grid, 256, 0, stream>>>(
        (const bf16*)hB, (const bf16*)WT2, b2, hB, N_NODES);
    // h3 = h2 + A h2         (gather bf16 hB -> hA)
    spmm_res_kernel<<<spmm_grid, 256, 0, stream>>>(hB, hA, rowptr, edges, N_NODES);
    // h4 = relu(h3 W3 + b3)  (in-place hA)
    gemm_relu_kernel<16><<<gemm_grid, 256, 0, stream>>>(
        (const bf16*)hA, (const bf16*)WT3, b3, hA, N_NODES);
    // out = log_softmax(h4 W4 + b4)
    gemm_ls_kernel<<<gemm_grid, 256, 0, stream>>>(
        (const bf16*)hA, (const bf16*)WT4, b4, (float*)d_out, N_NODES);
}

// Round 5
// 917.165 us; speedup vs baseline: 1.5820x; 1.0105x over previous
//
#include <hip/hip_runtime.h>
#include <hip/hip_bf16.h>
#include <cstdint>

#define N_NODES 100000
#define N_EDGES 3200000
#define NFEAT   256
#define NCLASS  40

// bucket sort params: bucket = row >> 7 (128 rows/bucket)
#define BROWS_LOG 7
#define BROWS     128
#define NBUCK     782      // ceil(100000/128)
#define CHUNK     8192     // edges per block in phase 1
#define NBLK      391      // ceil(3200000/8192)
#define GHN       (NBUCK * NBLK)   // 305762

// h-tile pitch in LDS (ushorts): 264*2 = 528 B = 33*16 -> 16B-aligned rows.
#define HP 264

typedef __bf16 bf16;
typedef __attribute__((ext_vector_type(8))) __bf16 bf16x8;
typedef __attribute__((ext_vector_type(4))) float f32x4;
typedef __attribute__((ext_vector_type(2))) float f32x2;

__device__ inline float b2f(unsigned short u) {
    union { unsigned int i; float f; } x; x.i = ((unsigned int)u) << 16; return x.f;
}
__device__ inline unsigned short f2b(float f) {
    union { float f; unsigned int i; } x; x.f = f;
    unsigned int i = x.i;
    return (unsigned short)((i + 0x7fffu + ((i >> 16) & 1u)) >> 16);
}
__device__ inline f32x2 unpack2(unsigned int d) {
    union { unsigned int i; float f; } lo, hi;
    lo.i = d << 16;
    hi.i = d & 0xFFFF0000u;
    return (f32x2){lo.f, hi.f};
}
__device__ inline unsigned int pack2(f32x2 a) {
    return ((unsigned int)f2b(a[0])) | (((unsigned int)f2b(a[1])) << 16);
}

// ---------------- weight transposes (fp32 W[k][n] -> bf16 WT[n][k]) ----------------
__global__ void prep_w_kernel(const float* __restrict__ W1, const float* __restrict__ W2,
                              const float* __restrict__ W3, const float* __restrict__ W4,
                              unsigned short* __restrict__ WT1, unsigned short* __restrict__ WT2,
                              unsigned short* __restrict__ WT3, unsigned short* __restrict__ WT4) {
    int i = blockIdx.x * blockDim.x + threadIdx.x;
    if (i < 256 * 256) {
        int nIdx = i >> 8, k = i & 255;
        WT1[i] = f2b(W1[k * 256 + nIdx]);
        WT2[i] = f2b(W2[k * 256 + nIdx]);
        WT3[i] = f2b(W3[k * 256 + nIdx]);
    }
    if (i < 48 * 256) {
        int nIdx = i >> 8, k = i & 255;
        WT4[i] = (nIdx < NCLASS) ? f2b(W4[k * NCLASS + nIdx]) : (unsigned short)0;
    }
}

// ---------------- fp32 -> bf16 cast ----------------
__global__ void cast_kernel(const float* __restrict__ X, unsigned short* __restrict__ Y, int n4) {
    int i = blockIdx.x * blockDim.x + threadIdx.x;
    if (i >= n4) return;
    float4 v = *(const float4*)(X + (size_t)i * 4);
    ushort4 o;
    o.x = f2b(v.x); o.y = f2b(v.y); o.z = f2b(v.z); o.w = f2b(v.w);
    *(ushort4*)(Y + (size_t)i * 4) = o;
}

// ---------------- P1a: per-(block,bucket) histogram (LDS only) ----------------
__global__ __launch_bounds__(256) void p1a_kernel(const int* __restrict__ erow,
                                                  int* __restrict__ ghist) {
    __shared__ int h[NBUCK];
    for (int j = threadIdx.x; j < NBUCK; j += 256) h[j] = 0;
    __syncthreads();
    int base = blockIdx.x * CHUNK;
    for (int j = 0; j < CHUNK; j += 256) {
        int i = base + j + threadIdx.x;
        if (i < N_EDGES) atomicAdd(&h[erow[i] >> BROWS_LOG], 1);
    }
    __syncthreads();
    for (int j = threadIdx.x; j < NBUCK; j += 256)
        ghist[(size_t)j * NBLK + blockIdx.x] = h[j];
}

// ---------------- in-place exclusive scan over ghist (GHN ints) ----------------
__global__ void scanB_blocks_kernel(int* __restrict__ g, int* __restrict__ bsums, int n) {
    __shared__ int s[1024];
    int i = blockIdx.x * 1024 + threadIdx.x;
    int v = (i < n) ? g[i] : 0;
    s[threadIdx.x] = v;
    __syncthreads();
    for (int off = 1; off < 1024; off <<= 1) {
        int t = (threadIdx.x >= off) ? s[threadIdx.x - off] : 0;
        __syncthreads();
        s[threadIdx.x] += t;
        __syncthreads();
    }
    if (i < n) g[i] = s[threadIdx.x] - v;
    if (threadIdx.x == 1023) bsums[blockIdx.x] = s[1023];
}

__global__ void scanB_sums_kernel(int* __restrict__ bsums, int nb) {
    __shared__ int s[512];
    int v = (threadIdx.x < nb) ? bsums[threadIdx.x] : 0;
    s[threadIdx.x] = v;
    __syncthreads();
    for (int off = 1; off < 512; off <<= 1) {
        int t = (threadIdx.x >= off) ? s[threadIdx.x - off] : 0;
        __syncthreads();
        s[threadIdx.x] += t;
        __syncthreads();
    }
    if (threadIdx.x < nb) bsums[threadIdx.x] = s[threadIdx.x] - v;  // exclusive
}

__global__ void scanB_add_kernel(int* __restrict__ g, const int* __restrict__ bsums, int n) {
    int i = blockIdx.x * blockDim.x + threadIdx.x;
    if (i < n) g[i] += bsums[i >> 10];
}

// ---------------- P1c: bucket scatter via LDS cursors (no global atomics) ----------------
__global__ __launch_bounds__(256) void p1c_kernel(const int* __restrict__ erow,
                                                  const int* __restrict__ ecol,
                                                  const float* __restrict__ ew,
                                                  const int* __restrict__ ghist,
                                                  uint2* __restrict__ stage) {
    __shared__ int cur[NBUCK];
    for (int j = threadIdx.x; j < NBUCK; j += 256)
        cur[j] = ghist[(size_t)j * NBLK + blockIdx.x];
    __syncthreads();
    int base = blockIdx.x * CHUNK;
    for (int j = 0; j < CHUNK; j += 1024) {
        int r[4], c[4]; float w[4]; bool m[4];
#pragma unroll
        for (int q = 0; q < 4; q++) {
            int i = base + j + q * 256 + threadIdx.x;
            m[q] = (i < N_EDGES);
            if (m[q]) { r[q] = erow[i]; c[q] = ecol[i]; w[q] = ew[i]; }
        }
#pragma unroll
        for (int q = 0; q < 4; q++) {
            if (m[q]) {
                unsigned int qq = (unsigned int)(w[q] * 32768.f + 0.5f);
                if (qq > 32767u) qq = 32767u;
                int p = atomicAdd(&cur[r[q] >> BROWS_LOG], 1);
                stage[p] = make_uint2((unsigned int)r[q], (((unsigned int)c[q]) << 15) | qq);
            }
        }
    }
}

// ---------------- P2: per-bucket local sort -> final edges + rowptr ----------------
__global__ __launch_bounds__(256) void p2_kernel(const int* __restrict__ ghist,
                                                 const uint2* __restrict__ stage,
                                                 unsigned int* __restrict__ edges,
                                                 int* __restrict__ rowptr) {
    __shared__ int h[BROWS], sc[BROWS], lcur[BROWS];
    int b = blockIdx.x;
    int lo = ghist[(size_t)b * NBLK];
    int hi = (b + 1 < NBUCK) ? ghist[(size_t)(b + 1) * NBLK] : N_EDGES;
    if (threadIdx.x < BROWS) h[threadIdx.x] = 0;
    __syncthreads();
    for (int i = lo + threadIdx.x; i < hi; i += 256)
        atomicAdd(&h[stage[i].x & (BROWS - 1)], 1);
    __syncthreads();
    if (threadIdx.x < BROWS) sc[threadIdx.x] = h[threadIdx.x];
    __syncthreads();
    for (int off = 1; off < BROWS; off <<= 1) {
        int t = 0;
        if (threadIdx.x < BROWS && threadIdx.x >= off) t = sc[threadIdx.x - off];
        __syncthreads();
        if (threadIdx.x < BROWS) sc[threadIdx.x] += t;
        __syncthreads();
    }
    if (threadIdx.x < BROWS) {
        int ex = sc[threadIdx.x] - h[threadIdx.x];   // exclusive
        int row = b * BROWS + threadIdx.x;
        if (row <= N_NODES) rowptr[row] = lo + ex;   // covers rowptr[N] exactly once
        lcur[threadIdx.x] = lo + ex;
    }
    __syncthreads();
    for (int i = lo + threadIdx.x; i < hi; i += 256) {
        uint2 sd = stage[i];
        int p = atomicAdd(&lcur[sd.x & (BROWS - 1)], 1);
        edges[p] = sd.y;
    }
}

// ---------------- SpMM + residual: Y = X + A*X (bf16 X/Y) ----------------
// (proven kernel, unchanged: 73% occupancy, ~3.7 TB/s)
__global__ void spmm_res_kernel(const unsigned short* __restrict__ X, unsigned short* __restrict__ Y,
                                const int* __restrict__ rowptr, const unsigned int* __restrict__ edges,
                                int n) {
    int gtid = blockIdx.x * blockDim.x + threadIdx.x;
    int row = gtid >> 6;
    int lane = gtid & 63;
    if (row >= n) return;
    const int half = lane >> 5;
    const int fb = (lane & 31) * 8;

    f32x2 acc[4];
    {
        uint4 xb = *(const uint4*)(X + (size_t)row * NFEAT + fb);
        if (half == 0) {
            acc[0] = unpack2(xb.x); acc[1] = unpack2(xb.y);
            acc[2] = unpack2(xb.z); acc[3] = unpack2(xb.w);
        } else {
            acc[0] = (f32x2){0.f, 0.f}; acc[1] = (f32x2){0.f, 0.f};
            acc[2] = (f32x2){0.f, 0.f}; acc[3] = (f32x2){0.f, 0.f};
        }
    }

    int s = rowptr[row], e = rowptr[row + 1];
    for (int k = s; k < e; k += 12) {
        int   c[6];
        f32x2 w2[6];
#pragma unroll
        for (int j = 0; j < 6; j++) {
            int kj = k + j * 2 + half;
            int kc = (kj < e) ? kj : (e - 1);
            unsigned int d = edges[kc];
            c[j] = (int)(d >> 15);
            float w = (kj < e) ? (float)(d & 32767u) * (1.f / 32768.f) : 0.f;
            w2[j] = (f32x2){w, w};
        }
        uint4 v[6];
#pragma unroll
        for (int j = 0; j < 6; j++) v[j] = *(const uint4*)(X + (size_t)c[j] * NFEAT + fb);
#pragma unroll
        for (int j = 0; j < 6; j++) {
            acc[0] += w2[j] * unpack2(v[j].x);
            acc[1] += w2[j] * unpack2(v[j].y);
            acc[2] += w2[j] * unpack2(v[j].z);
            acc[3] += w2[j] * unpack2(v[j].w);
        }
    }

#pragma unroll
    for (int i = 0; i < 4; i++) {
        acc[i][0] += __shfl_xor(acc[i][0], 32, 64);
        acc[i][1] += __shfl_xor(acc[i][1], 32, 64);
    }
    if (half == 0) {
        uint4 o;
        o.x = pack2(acc[0]); o.y = pack2(acc[1]);
        o.z = pack2(acc[2]); o.w = pack2(acc[3]);
        *(uint4*)(Y + (size_t)row * NFEAT + fb) = o;
    }
}

// ---------------- fused GEMM1+GEMM2: h2 = relu(relu(X W1 + b1) W2 + b2) ----------------
// Swapped-operand MFMA (lane (m,quad) owns one node row). h1 lives only in LDS
// (64x256 bf16 tile, pitch HP): saves the 100 MB h1 HBM round-trip + a launch.
// h1 passes through the same f2b(relu(...)) rounding as before -> bit-identical.
__global__ __launch_bounds__(256) void gemm12_kernel(
    const bf16* __restrict__ X,
    const bf16* __restrict__ WT1, const float* __restrict__ b1,
    const bf16* __restrict__ WT2, const float* __restrict__ b2,
    unsigned short* __restrict__ Y, int M) {
    __shared__ unsigned int sB[256 * 20];       // 20480 B weight staging
    __shared__ unsigned short sH[64 * HP];      // 33792 B h1 tile
    const int tid = threadIdx.x;
    const int wave = tid >> 6;
    const int lane = tid & 63;
    const int m = lane & 15;
    const int quad = lane >> 4;
    const int lrow = wave * 16 + m;             // 0..63 within block
    const int rowBase = blockIdx.x * 64;
    int arow = rowBase + lrow;
    if (arow >= M) arow = M - 1;

    f32x4 acc[16];
#pragma unroll
    for (int t = 0; t < 16; t++) acc[t] = (f32x4){0.f, 0.f, 0.f, 0.f};

    // ---- phase A: h1 = relu(X W1 + b1) -> sH ----
    const bf16* xp = X + (size_t)arow * NFEAT + quad * 8;
#pragma unroll
    for (int k0 = 0; k0 < NFEAT; k0 += 32) {
#pragma unroll
        for (int f = tid; f < 1024; f += 256) {
            int n = f >> 2, j = f & 3;
            uint4 v = *(const uint4*)((const unsigned short*)WT1 + (size_t)n * NFEAT + k0 + j * 8);
            *(uint4*)&sB[n * 20 + j * 4] = v;
        }
        __syncthreads();
        bf16x8 a = *(const bf16x8*)(xp + k0);
#pragma unroll
        for (int t = 0; t < 16; t++) {
            bf16x8 b = *(const bf16x8*)&sB[(t * 16 + m) * 20 + quad * 4];
            acc[t] = __builtin_amdgcn_mfma_f32_16x16x32_bf16(b, a, acc[t], 0, 0, 0);
        }
        __syncthreads();
    }
#pragma unroll
    for (int t = 0; t < 16; t++) {
        const float* bp = b1 + t * 16 + quad * 4;
        f32x2 lo = (f32x2){fmaxf(acc[t][0] + bp[0], 0.f), fmaxf(acc[t][1] + bp[1], 0.f)};
        f32x2 hi = (f32x2){fmaxf(acc[t][2] + bp[2], 0.f), fmaxf(acc[t][3] + bp[3], 0.f)};
        *(uint2*)&sH[lrow * HP + t * 16 + quad * 4] = make_uint2(pack2(lo), pack2(hi));
        acc[t] = (f32x4){0.f, 0.f, 0.f, 0.f};
    }
    __syncthreads();   // sH complete before phase B reads (and before sB reuse)

    // ---- phase B: h2 = relu(h1 W2 + b2) -> global ----
#pragma unroll
    for (int k0 = 0; k0 < NFEAT; k0 += 32) {
#pragma unroll
        for (int f = tid; f < 1024; f += 256) {
            int n = f >> 2, j = f & 3;
            uint4 v = *(const uint4*)((const unsigned short*)WT2 + (size_t)n * NFEAT + k0 + j * 8);
            *(uint4*)&sB[n * 20 + j * 4] = v;
        }
        __syncthreads();
        bf16x8 a = *(const bf16x8*)&sH[lrow * HP + k0 + quad * 8];
#pragma unroll
        for (int t = 0; t < 16; t++) {
            bf16x8 b = *(const bf16x8*)&sB[(t * 16 + m) * 20 + quad * 4];
            acc[t] = __builtin_amdgcn_mfma_f32_16x16x32_bf16(b, a, acc[t], 0, 0, 0);
        }
        __syncthreads();
    }
    const int row = rowBase + lrow;
    if (row < M) {
#pragma unroll
        for (int t = 0; t < 16; t++) {
            const float* bp = b2 + t * 16 + quad * 4;
            f32x2 lo = (f32x2){fmaxf(acc[t][0] + bp[0], 0.f), fmaxf(acc[t][1] + bp[1], 0.f)};
            f32x2 hi = (f32x2){fmaxf(acc[t][2] + bp[2], 0.f), fmaxf(acc[t][3] + bp[3], 0.f)};
            *(uint2*)(Y + (size_t)row * NFEAT + t * 16 + quad * 4) = make_uint2(pack2(lo), pack2(hi));
        }
    }
}

// ---------------- fused GEMM3 + final GEMM4 + log_softmax ----------------
// out = log_softmax(relu(X W3 + b3) W4 + b4); h4 lives only in LDS.
__global__ __launch_bounds__(256) void gemm34_ls_kernel(
    const bf16* __restrict__ X,
    const bf16* __restrict__ WT3, const float* __restrict__ b3,
    const bf16* __restrict__ WT4, const float* __restrict__ b4,
    float* __restrict__ out, int M) {
    __shared__ unsigned int sB[256 * 20];
    __shared__ unsigned short sH[64 * HP];
    const int tid = threadIdx.x;
    const int wave = tid >> 6;
    const int lane = tid & 63;
    const int m = lane & 15;
    const int quad = lane >> 4;
    const int lrow = wave * 16 + m;
    const int rowBase = blockIdx.x * 64;
    int arow = rowBase + lrow;
    if (arow >= M) arow = M - 1;

    f32x4 acc[16];
#pragma unroll
    for (int t = 0; t < 16; t++) acc[t] = (f32x4){0.f, 0.f, 0.f, 0.f};

    // ---- phase A: h4 = relu(X W3 + b3) -> sH ----
    const bf16* xp = X + (size_t)arow * NFEAT + quad * 8;
#pragma unroll
    for (int k0 = 0; k0 < NFEAT; k0 += 32) {
#pragma unroll
        for (int f = tid; f < 1024; f += 256) {
            int n = f >> 2, j = f & 3;
            uint4 v = *(const uint4*)((const unsigned short*)WT3 + (size_t)n * NFEAT + k0 + j * 8);
            *(uint4*)&sB[n * 20 + j * 4] = v;
        }
        __syncthreads();
        bf16x8 a = *(const bf16x8*)(xp + k0);
#pragma unroll
        for (int t = 0; t < 16; t++) {
            bf16x8 b = *(const bf16x8*)&sB[(t * 16 + m) * 20 + quad * 4];
            acc[t] = __builtin_amdgcn_mfma_f32_16x16x32_bf16(b, a, acc[t], 0, 0, 0);
        }
        __syncthreads();
    }
#pragma unroll
    for (int t = 0; t < 16; t++) {
        const float* bp = b3 + t * 16 + quad * 4;
        f32x2 lo = (f32x2){fmaxf(acc[t][0] + bp[0], 0.f), fmaxf(acc[t][1] + bp[1], 0.f)};
        f32x2 hi = (f32x2){fmaxf(acc[t][2] + bp[2], 0.f), fmaxf(acc[t][3] + bp[3], 0.f)};
        *(uint2*)&sH[lrow * HP + t * 16 + quad * 4] = make_uint2(pack2(lo), pack2(hi));
    }
    __syncthreads();

    // ---- phase B: z = h4 W4 + b4 (48 cols, 40 valid) + log_softmax ----
    f32x4 a4[3];
#pragma unroll
    for (int t = 0; t < 3; t++) a4[t] = (f32x4){0.f, 0.f, 0.f, 0.f};
#pragma unroll
    for (int k0 = 0; k0 < NFEAT; k0 += 32) {
        if (tid < 192) {
            int n = tid >> 2, j = tid & 3;
            uint4 v = *(const uint4*)((const unsigned short*)WT4 + (size_t)n * NFEAT + k0 + j * 8);
            *(uint4*)&sB[n * 20 + j * 4] = v;
        }
        __syncthreads();
        bf16x8 a = *(const bf16x8*)&sH[lrow * HP + k0 + quad * 8];
#pragma unroll
        for (int t = 0; t < 3; t++) {
            bf16x8 b = *(const bf16x8*)&sB[(t * 16 + m) * 20 + quad * 4];
            a4[t] = __builtin_amdgcn_mfma_f32_16x16x32_bf16(b, a, a4[t], 0, 0, 0);
        }
        __syncthreads();
    }

    // lane (m,quad) owns row rowBase+lrow, cols t*16+quad*4+{0..3}
    // valid cols < 40: t=0,1 all; t=2 only quad<2.
    float v[3][4];
#pragma unroll
    for (int t = 0; t < 3; t++) {
        bool tv = (t < 2) || (quad < 2);
#pragma unroll
        for (int r = 0; r < 4; r++) {
            float bv = tv ? b4[t * 16 + quad * 4 + r] : 0.f;
            v[t][r] = tv ? (a4[t][r] + bv) : -1e30f;
        }
    }

    float mx = -1e30f;
#pragma unroll
    for (int t = 0; t < 3; t++)
#pragma unroll
        for (int r = 0; r < 4; r++) mx = fmaxf(mx, v[t][r]);
    mx = fmaxf(mx, __shfl_xor(mx, 16, 64));
    mx = fmaxf(mx, __shfl_xor(mx, 32, 64));

    float sm = 0.f;
#pragma unroll
    for (int t = 0; t < 3; t++) {
        bool tv = (t < 2) || (quad < 2);
        if (tv) {
#pragma unroll
            for (int r = 0; r < 4; r++) sm += __expf(v[t][r] - mx);
        }
    }
    sm += __shfl_xor(sm, 16, 64);
    sm += __shfl_xor(sm, 32, 64);
    float ls = __logf(sm);

    const int row = rowBase + lrow;
    if (row < M) {
#pragma unroll
        for (int t = 0; t < 3; t++) {
            if ((t < 2) || (quad < 2)) {
                f32x4 o = (f32x4){v[t][0] - mx - ls, v[t][1] - mx - ls,
                                  v[t][2] - mx - ls, v[t][3] - mx - ls};
                *(f32x4*)(out + (size_t)row * NCLASS + t * 16 + quad * 4) = o;
            }
        }
    }
}

extern "C" void kernel_launch(void* const* d_in, const int* in_sizes, int n_in,
                              void* d_out, int out_size, void* d_ws, size_t ws_size,
                              hipStream_t stream) {
    const float* x   = (const float*)d_in[0];
    const int* erow  = (const int*)d_in[1];
    const int* ecol  = (const int*)d_in[2];
    const float* ew  = (const float*)d_in[3];
    const float* W1  = (const float*)d_in[4];
    const float* W2  = (const float*)d_in[6];
    const float* W3  = (const float*)d_in[8];
    const float* W4  = (const float*)d_in[10];
    const float* b1  = (const float*)d_in[5];
    const float* b2  = (const float*)d_in[7];
    const float* b3  = (const float*)d_in[9];
    const float* b4  = (const float*)d_in[11];

    char* ws = (char*)d_ws;
    size_t off = 0;
    auto alloc = [&](size_t bytes) -> char* {
        char* p = ws + off;
        off = (off + bytes + 255) & ~(size_t)255;
        return p;
    };
    // stage (25.6 MB) aliases the front of hA: stage's lifetime is [p1c, p2];
    // hA is written by cast_kernel AFTER p2. hB reuses the x input buffer
    // (fp32 x dead after cast; harness restores d_in before every launch).
    int* rowptr  = (int*)alloc((size_t)(N_NODES + 1) * 4);
    int* bsumsB  = (int*)alloc(512 * 4);
    unsigned int* edges = (unsigned int*)alloc((size_t)N_EDGES * 4);  // packed col|w
    int* ghist   = (int*)alloc((size_t)GHN * 4);
    unsigned short* WT1 = (unsigned short*)alloc(256 * 256 * 2);
    unsigned short* WT2 = (unsigned short*)alloc(256 * 256 * 2);
    unsigned short* WT3 = (unsigned short*)alloc(256 * 256 * 2);
    unsigned short* WT4 = (unsigned short*)alloc(48 * 256 * 2);
    unsigned short* hA  = (unsigned short*)alloc((size_t)N_NODES * NFEAT * 2);
    uint2* stage        = (uint2*)hA;                      // aliased (see above)
    unsigned short* hB  = (unsigned short*)d_in[0];
    (void)ws_size; (void)n_in; (void)in_sizes; (void)out_size;

    // ---- atomic-free CSR build ----
    prep_w_kernel<<<(256 * 256 + 255) / 256, 256, 0, stream>>>(
        W1, W2, W3, W4, WT1, WT2, WT3, WT4);
    p1a_kernel<<<NBLK, 256, 0, stream>>>(erow, ghist);
    int nsb = (GHN + 1023) / 1024;   // 299
    scanB_blocks_kernel<<<nsb, 1024, 0, stream>>>(ghist, bsumsB, GHN);
    scanB_sums_kernel<<<1, 512, 0, stream>>>(bsumsB, nsb);
    scanB_add_kernel<<<(GHN + 255) / 256, 256, 0, stream>>>(ghist, bsumsB, GHN);
    p1c_kernel<<<NBLK, 256, 0, stream>>>(erow, ecol, ew, ghist, stage);
    p2_kernel<<<NBUCK, 256, 0, stream>>>(ghist, stage, edges, rowptr);

    // ---- forward pass ----
    const int n4 = N_NODES * NFEAT / 4;
    const int spmm_grid = (N_NODES * 64 + 255) / 256;
    const int gemm_grid = (N_NODES + 63) / 64;

    // xb16 = bf16(x)  (after p2: stage region is dead, hA is safe to write)
    cast_kernel<<<(n4 + 255) / 256, 256, 0, stream>>>(x, hA, n4);
    // h0 = x + A x           (gather bf16 hA -> hB)
    spmm_res_kernel<<<spmm_grid, 256, 0, stream>>>(hA, hB, rowptr, edges, N_NODES);
    // h2 = relu(relu(h0 W1 + b1) W2 + b2)   (in-place hB; h1 LDS-only)
    gemm12_kernel<<<gemm_grid, 256, 0, stream>>>(
        (const bf16*)hB, (const bf16*)WT1, b1, (const bf16*)WT2, b2, hB, N_NODES);
    // h3 = h2 + A h2         (gather bf16 hB -> hA)
    spmm_res_kernel<<<spmm_grid, 256, 0, stream>>>(hB, hA, rowptr, edges, N_NODES);
    // out = log_softmax(relu(h3 W3 + b3) W4 + b4)   (h4 LDS-only)
    gemm34_ls_kernel<<<gemm_grid, 256, 0, stream>>>(
        (const bf16*)hA, (const bf16*)WT3, b3, (const bf16*)WT4, b4, (float*)d_out, N_NODES);
}